// Round 14
// baseline (922.601 us; speedup 1.0000x reference)
//
#include <hip/hip_runtime.h>

#define B_   32
#define T_   300
#define C1_  2312
#define O1_  512
#define O2_  512
#define O3_  10
#define M_   (B_*T_)   // 9600
#define KSPLIT_ 1152   // 72 tiles of 16; half1 = 73 tiles (tail-guarded)

// ---------------- weight prep (all f64) ----------------

__global__ void calc_f(const float* __restrict__ v, const float* __restrict__ g,
                       double* __restrict__ f, int O, int C) {
    int o = blockIdx.x;
    const float* row = v + (size_t)o * C;
    double s = 0.0;
    for (int c = threadIdx.x; c < C; c += blockDim.x) {
        double x = (double)row[c];
        s += x * x;
    }
    for (int off = 32; off; off >>= 1) s += __shfl_down(s, off);
    __shared__ double wsum[4];
    int lane = threadIdx.x & 63, wv = threadIdx.x >> 6;
    if (lane == 0) wsum[wv] = s;
    __syncthreads();
    if (threadIdx.x == 0) {
        double tot = 0.0;
        for (int i = 0; i < (int)(blockDim.x >> 6); ++i) tot += wsum[i];
        f[o] = (double)g[o] / sqrt(tot);
    }
}

// wt[c*ldo + o] = v[o*C + c] * f[o]   (double)
__global__ void transpose_scale(const float* __restrict__ v, const double* __restrict__ f,
                                double* __restrict__ wt, int O, int C, int ldo) {
    __shared__ double tile[32][33];
    int c0 = blockIdx.x * 32, o0 = blockIdx.y * 32;
    int tx = threadIdx.x, ty = threadIdx.y;
    for (int k = 0; k < 4; ++k) {
        int o = o0 + ty + k * 8, c = c0 + tx;
        double val = 0.0;
        if (o < O && c < C) val = (double)v[(size_t)o * C + c] * f[o];
        tile[ty + k * 8][tx] = val;
    }
    __syncthreads();
    for (int k = 0; k < 4; ++k) {
        int c = c0 + ty + k * 8, o = o0 + tx;
        if (c < C && o < O) wt[(size_t)c * ldo + o] = tile[tx][ty + k * 8];
    }
}

// ---------------- spike -> bitmask precompute ----------------
// bits[(b*C1 + c)*10 + t32] : bit j = (X[b][c][t32*32+j] != 0)
__global__ void build_bits(const float* __restrict__ X, unsigned* __restrict__ bits) {
    size_t idx = (size_t)blockIdx.x * 256 + threadIdx.x;
    if (idx >= (size_t)B_ * C1_ * 10) return;
    int t32 = (int)(idx % 10);
    size_t bc = idx / 10;
    const float* src = X + bc * T_ + t32 * 32;
    int nq = (t32 == 9) ? 3 : 8;   // 12 or 32 valid t's (T_=300)
    unsigned m = 0;
    for (int q = 0; q < nq; ++q) {
        float4 v = *(const float4*)(src + q * 4);
        if (v.x != 0.f) m |= 1u << (q * 4 + 0);
        if (v.y != 0.f) m |= 1u << (q * 4 + 1);
        if (v.z != 0.f) m |= 1u << (q * 4 + 2);
        if (v.w != 0.f) m |= 1u << (q * 4 + 3);
    }
    bits[idx] = m;
}

// ---------------- GEMM layer 1 (f64, Xbits + SGPR-branch skip) -- R13 verbatim ----------------
__global__ __launch_bounds__(256) void gemm1(const unsigned* __restrict__ Xbits,
                                             const double* __restrict__ Wt,
                                             double* __restrict__ Z) {
    __shared__ double Ws[16][256];   // [k][o] 32 KB
    int zb = blockIdx.z;
    int b = zb >> 1, khalf = zb & 1;
    int cbeg = khalf ? KSPLIT_ : 0;
    const int NT = khalf ? 73 : 72;
    int o0 = blockIdx.y * 256;
    int tb = blockIdx.x;                 // 32-t window index (0..9)
    int tid = threadIdx.x;
    int lane = tid & 63;
    int w8s = __builtin_amdgcn_readfirstlane((tid >> 6) << 3);  // wave's t-octet offset
    double acc[8][4];
#pragma unroll
    for (int tj = 0; tj < 8; ++tj)
#pragma unroll
        for (int i = 0; i < 4; ++i) acc[tj][i] = 0.0;
    const unsigned* xbp = Xbits + (size_t)b * C1_ * 10 + tb;

    double2 wreg[8];
    unsigned mk[16], mkn[16];

    auto load_w = [&](int c0) {
#pragma unroll
        for (int h = 0; h < 8; ++h) {
            int idx = h * 256 + tid;
            int i = idx >> 7, od = (idx & 127) * 2;
            int c = c0 + i;
            double2 val; val.x = 0.0; val.y = 0.0;
            if (c < C1_) val = *(const double2*)(Wt + (size_t)c * O1_ + o0 + od);
            wreg[h] = val;
        }
    };
    auto load_m = [&](unsigned* dst, int c0) {
#pragma unroll
        for (int k = 0; k < 16; ++k) {
            int c = c0 + k;
            dst[k] = (c < C1_) ? xbp[(size_t)c * 10] : 0u;
        }
    };
    auto store_w = [&]() {
#pragma unroll
        for (int h = 0; h < 8; ++h) {
            int idx = h * 256 + tid;
            int i = idx >> 7, od = (idx & 127) * 2;
            *(double2*)(&Ws[i][od]) = wreg[h];
        }
    };

    load_w(cbeg);
    load_m(mk, cbeg);
    for (int tile = 0; tile < NT; ++tile) {
        store_w();
        __syncthreads();
        if (tile + 1 < NT) {
            int cn = cbeg + (tile + 1) * 16;
            load_w(cn);
            load_m(mkn, cn);
        }
#pragma unroll
        for (int k = 0; k < 16; ++k) {
            unsigned smk = (unsigned)__builtin_amdgcn_readfirstlane((int)mk[k]);
            unsigned soct = (smk >> w8s) & 0xffu;
            if (soct) {
                double wf[4];
#pragma unroll
                for (int i = 0; i < 4; ++i) wf[i] = Ws[k][lane + 64 * i];
#pragma unroll
                for (int tj = 0; tj < 8; ++tj) {
                    if (soct & (1u << tj)) {
#pragma unroll
                        for (int i = 0; i < 4; ++i) acc[tj][i] += wf[i];
                    }
                }
            }
        }
#pragma unroll
        for (int k = 0; k < 16; ++k) mk[k] = mkn[k];
        __syncthreads();
    }
#pragma unroll
    for (int tj = 0; tj < 8; ++tj) {
        int t = tb * 32 + w8s + tj;
        if (t < T_) {
            double* dst = Z + ((size_t)b * T_ + t) * O1_ + o0;
#pragma unroll
            for (int i = 0; i < 4; ++i)
                atomicAdd(&dst[lane + 64 * i], acc[tj][i]);
        }
    }
}

// ---------------- GEMM layer 2 (f64, gemm1 clone on s1 bitmasks) ----------------
// Sbits: [B, 512, 10] u32 (delayed s1 spikes) ; Wt: [512, 512] f64 ; Z: [B, T, 512] f64
// K=512 = 32 tiles, no K-split, direct stores. Same ascending-c order with
// exact-zero terms elided -> z2 bit-identical to dense f64 fma.
__global__ __launch_bounds__(256) void gemm2(const unsigned* __restrict__ Sbits,
                                             const double* __restrict__ Wt,
                                             double* __restrict__ Z) {
    __shared__ double Ws[16][256];
    int b  = blockIdx.z;
    int o0 = blockIdx.y * 256;
    int tb = blockIdx.x;
    int tid = threadIdx.x;
    int lane = tid & 63;
    int w8s = __builtin_amdgcn_readfirstlane((tid >> 6) << 3);
    double acc[8][4];
#pragma unroll
    for (int tj = 0; tj < 8; ++tj)
#pragma unroll
        for (int i = 0; i < 4; ++i) acc[tj][i] = 0.0;
    const unsigned* xbp = Sbits + (size_t)b * 512 * 10 + tb;

    double2 wreg[8];
    unsigned mk[16], mkn[16];

    auto load_w = [&](int c0) {
#pragma unroll
        for (int h = 0; h < 8; ++h) {
            int idx = h * 256 + tid;
            int i = idx >> 7, od = (idx & 127) * 2;
            wreg[h] = *(const double2*)(Wt + (size_t)(c0 + i) * 512 + o0 + od);
        }
    };
    auto load_m = [&](unsigned* dst, int c0) {
#pragma unroll
        for (int k = 0; k < 16; ++k) dst[k] = xbp[(size_t)(c0 + k) * 10];
    };
    auto store_w = [&]() {
#pragma unroll
        for (int h = 0; h < 8; ++h) {
            int idx = h * 256 + tid;
            int i = idx >> 7, od = (idx & 127) * 2;
            *(double2*)(&Ws[i][od]) = wreg[h];
        }
    };

    load_w(0);
    load_m(mk, 0);
    for (int tile = 0; tile < 32; ++tile) {
        store_w();
        __syncthreads();
        if (tile + 1 < 32) {
            int cn = (tile + 1) * 16;
            load_w(cn);
            load_m(mkn, cn);
        }
#pragma unroll
        for (int k = 0; k < 16; ++k) {
            unsigned smk = (unsigned)__builtin_amdgcn_readfirstlane((int)mk[k]);
            unsigned soct = (smk >> w8s) & 0xffu;
            if (soct) {
                double wf[4];
#pragma unroll
                for (int i = 0; i < 4; ++i) wf[i] = Ws[k][lane + 64 * i];
#pragma unroll
                for (int tj = 0; tj < 8; ++tj) {
                    if (soct & (1u << tj)) {
#pragma unroll
                        for (int i = 0; i < 4; ++i) acc[tj][i] += wf[i];
                    }
                }
            }
        }
#pragma unroll
        for (int k = 0; k < 16; ++k) mk[k] = mkn[k];
        __syncthreads();
    }
#pragma unroll
    for (int tj = 0; tj < 8; ++tj) {
        int t = tb * 32 + w8s + tj;
        if (t < T_) {
            double* dst = Z + ((size_t)b * T_ + t) * O1_ + o0;
#pragma unroll
            for (int i = 0; i < 4; ++i) dst[lane + 64 * i] = acc[tj][i];
        }
    }
}

// ---------------- GEMM layer 3 (f64 acc) ----------------
__global__ __launch_bounds__(256) void gemm3(const float* __restrict__ A,
                                             const double* __restrict__ Wt,
                                             double* __restrict__ Z) {
    __shared__ double w[512 * 16];
    for (int e = threadIdx.x; e < 4096; e += 256)
        ((double2*)w)[e] = ((const double2*)Wt)[e];
    __syncthreads();
    int m = blockIdx.x * 256 + threadIdx.x;
    if (m >= M_) return;
    double acc[O3_];
#pragma unroll
    for (int o = 0; o < O3_; ++o) acc[o] = 0.0;
    const float4* Ar = (const float4*)(A + (size_t)m * 512);
    for (int cq = 0; cq < 128; ++cq) {
        float4 a = Ar[cq];
        float av[4] = {a.x, a.y, a.z, a.w};
#pragma unroll
        for (int u = 0; u < 4; ++u)
#pragma unroll
            for (int o = 0; o < O3_; ++o) acc[o] += (double)av[u] * w[(cq * 4 + u) * 16 + o];
    }
    double* dst = Z + (size_t)m * 16;
#pragma unroll
    for (int o = 0; o < O3_; ++o) dst[o] = acc[o];
}

// ---------------- LIF scan + delay, layers 1/2 (O=512, f64 state) ----------------
// If bitsOut != nullptr: emit delayed spikes as bitmasks [B,512,10] u32
// (bit tw&31 of word tw>>5), NO float stores. Else: float stores (for gemm3).
// tw = t + d is monotone; mi runs 0..9 for every thread (last tw == 299).
__global__ void scan12(const double* __restrict__ Zin,  // [B, T, 512] f64
                       const int* __restrict__ delay,   // [512]
                       float* __restrict__ Sout,        // [B, T, 512] f32 (may be unused)
                       unsigned* __restrict__ bitsOut,  // [B, 512, 10] u32 or nullptr
                       float* __restrict__ sumOut) {
    int blk = blockIdx.x;
    int o = (blk & 7) * 64 + threadIdx.x;
    int b = blk >> 3;
    const double* z = Zin + (size_t)b * T_ * O1_ + o;
    float* s = Sout + (size_t)b * T_ * O1_ + o;
    int d = delay[o];
    bool emitBits = (bitsOut != nullptr);
    unsigned* bout = emitBits ? (bitsOut + ((size_t)b * 512 + o) * 10) : nullptr;
    unsigned mcur = 0; int mi = 0;
    if (!emitBits)
        for (int t = 0; t < d; ++t) s[(size_t)t * O1_] = 0.f;
    double cur = 0.0, vol = 0.0;
    float cnt = 0.f;
    // 296 = 37*8; tail of 4 handled after.
    for (int t8 = 0; t8 < 296; t8 += 8) {
        double zb[8];
#pragma unroll
        for (int u = 0; u < 8; ++u) zb[u] = z[(size_t)(t8 + u) * O1_];
#pragma unroll
        for (int u = 0; u < 8; ++u) {
            int t = t8 + u;
            cur = cur * 0.75 + zb[u];
            vol = vol * 0.97 + cur;
            float sp = (vol >= 1.25) ? 1.f : 0.f;
            if (sp > 0.f) vol = 0.0;
            int tw = t + d;
            if (tw < T_) {
                if (emitBits) {
                    int w = tw >> 5;
                    if (w != mi) { bout[mi] = mcur; mcur = 0; mi = w; }
                    if (sp > 0.f) mcur |= 1u << (tw & 31);
                } else {
                    s[(size_t)tw * O1_] = sp;
                }
                cnt += sp;
            }
        }
    }
    {
        double zb[4];
#pragma unroll
        for (int u = 0; u < 4; ++u) zb[u] = z[(size_t)(296 + u) * O1_];
#pragma unroll
        for (int u = 0; u < 4; ++u) {
            int t = 296 + u;
            cur = cur * 0.75 + zb[u];
            vol = vol * 0.97 + cur;
            float sp = (vol >= 1.25) ? 1.f : 0.f;
            if (sp > 0.f) vol = 0.0;
            int tw = t + d;
            if (tw < T_) {
                if (emitBits) {
                    int w = tw >> 5;
                    if (w != mi) { bout[mi] = mcur; mcur = 0; mi = w; }
                    if (sp > 0.f) mcur |= 1u << (tw & 31);
                } else {
                    s[(size_t)tw * O1_] = sp;
                }
                cnt += sp;
            }
        }
    }
    if (emitBits) bout[mi] = mcur;   // mi == 9 for all threads
    for (int off = 32; off; off >>= 1) cnt += __shfl_down(cnt, off);
    if (threadIdx.x == 0) atomicAdd(sumOut, cnt);
}

// ---------------- LIF scan + delay, layer 3 (O=10, f64 state) ----------------
__global__ void scan3(const double* __restrict__ Z3,  // [M, 16] f64
                      const int* __restrict__ d3,     // [10]
                      float* __restrict__ out,        // d_out: [B, 10, 300] f32
                      float* __restrict__ sumOut) {
    __shared__ double zt[T_ * 16];
    int b = blockIdx.x;
    const double2* src = (const double2*)(Z3 + (size_t)b * T_ * 16);
    for (int e = threadIdx.x; e < T_ * 8; e += 64)
        ((double2*)zt)[e] = src[e];
    __syncthreads();
    int o = threadIdx.x;
    if (o < O3_) {
        int d = d3[o];
        float* dst = out + (size_t)b * O3_ * T_ + (size_t)o * T_;
        for (int t = 0; t < d; ++t) dst[t] = 0.f;
        double cur = 0.0, vol = 0.0;
        float cnt = 0.f;
        for (int t = 0; t < T_; ++t) {
            cur = cur * 0.75 + zt[t * 16 + o];
            vol = vol * 0.97 + cur;
            float sp = (vol >= 1.25) ? 1.f : 0.f;
            if (sp > 0.f) vol = 0.0;
            int tw = t + d;
            if (tw < T_) { dst[tw] = sp; cnt += sp; }
        }
        atomicAdd(sumOut, cnt);
    }
}

__global__ void finalize(const float* __restrict__ sums, float* __restrict__ out) {
    if (threadIdx.x == 0) {
        out[0] = (float)((double)sums[0] / (double)(B_ * O1_ * T_));
        out[1] = (float)((double)sums[1] / (double)(B_ * O2_ * T_));
        out[2] = (float)((double)sums[2] / (double)(B_ * O3_ * T_));
    }
}

extern "C" void kernel_launch(void* const* d_in, const int* in_sizes, int n_in,
                              void* d_out, int out_size, void* d_ws, size_t ws_size,
                              hipStream_t stream) {
    const float* spike = (const float*)d_in[0];
    const float* v1 = (const float*)d_in[1];
    const float* g1 = (const float*)d_in[2];
    const float* v2 = (const float*)d_in[3];
    const float* g2 = (const float*)d_in[4];
    const float* v3 = (const float*)d_in[5];
    const float* g3 = (const float*)d_in[6];
    const int* d1 = (const int*)d_in[7];
    const int* d2 = (const int*)d_in[8];
    const int* d3 = (const int*)d_in[9];
    float* out = (float*)d_out;

    // Workspace: ~78 MB (R13 layout + 2.6 MB Sbits).
    double* dw = (double*)d_ws;
    size_t off = 0;
    double* f1  = dw + off; off += 512;
    double* f2  = dw + off; off += 512;
    double* f3  = dw + off; off += 16;
    double* Wt1 = dw + off; off += (size_t)C1_ * O1_;
    double* Wt2 = dw + off; off += 512 * 512;
    double* Wt3 = dw + off; off += 512 * 16;
    double* zA  = dw + off; off += (size_t)M_ * 512;
    double* z3b = dw + off; off += (size_t)M_ * 16;
    float* fw = (float*)(dw + off);
    float* sB    = fw;                                   // f32 spikes (s2), M*512
    float* sums  = fw + (size_t)M_ * 512;                // 4 floats
    unsigned* Xbits = (unsigned*)(fw + (size_t)M_ * 512 + 4);      // B*C1*10 u32
    unsigned* Sbits = Xbits + (size_t)B_ * C1_ * 10;               // B*512*10 u32
    (void)ws_size; (void)out_size; (void)in_sizes; (void)n_in;

    hipMemsetAsync(sums, 0, 4 * sizeof(float), stream);
    hipMemsetAsync(zA, 0, (size_t)M_ * 512 * sizeof(double), stream);  // K-split atomics

    build_bits<<<(B_ * C1_ * 10 + 255) / 256, 256, 0, stream>>>(spike, Xbits);

    calc_f<<<512, 256, 0, stream>>>(v1, g1, f1, O1_, C1_);
    calc_f<<<512, 256, 0, stream>>>(v2, g2, f2, O2_, O1_);
    calc_f<<<O3_, 256, 0, stream>>>(v3, g3, f3, O3_, O2_);

    transpose_scale<<<dim3((C1_ + 31) / 32, 16), dim3(32, 8), 0, stream>>>(v1, f1, Wt1, O1_, C1_, O1_);
    transpose_scale<<<dim3(16, 16), dim3(32, 8), 0, stream>>>(v2, f2, Wt2, O2_, O1_, O2_);
    transpose_scale<<<dim3(16, 1), dim3(32, 8), 0, stream>>>(v3, f3, Wt3, O3_, O2_, 16);

    // gemm1: 10 t-windows x 2 o-halves(256) x (32 b x 2 k-halves) = 1280 blocks
    gemm1<<<dim3(10, 2, B_ * 2), 256, 0, stream>>>(Xbits, Wt1, zA);     // zA += z1
    scan12<<<256, 64, 0, stream>>>(zA, d1, sB, Sbits, sums + 0);        // Sbits = s1 (bits)
    // gemm2: 10 t-windows x 2 o-halves x 32 b = 640 blocks, sparse on Sbits
    gemm2<<<dim3(10, 2, B_), 256, 0, stream>>>(Sbits, Wt2, zA);         // zA = z2
    scan12<<<256, 64, 0, stream>>>(zA, d2, sB, nullptr, sums + 1);      // sB = s2 (f32)
    gemm3<<<(M_ + 255) / 256, 256, 0, stream>>>(sB, Wt3, z3b);          // z3b = z3
    scan3<<<B_, 64, 0, stream>>>(z3b, d3, out, sums + 2);
    finalize<<<1, 64, 0, stream>>>(sums, out + (size_t)B_ * O3_ * T_);
}

// Round 15
// 843.071 us; speedup vs baseline: 1.0943x; 1.0943x over previous
//
#include <hip/hip_runtime.h>

#define B_   32
#define T_   300
#define C1_  2312
#define O1_  512
#define O2_  512
#define O3_  10
#define M_   (B_*T_)   // 9600
#define KSPLIT_ 1152   // 72 tiles of 16; half1 = 73 tiles (tail-guarded)

// ---------------- weight prep (all f64) ----------------

__global__ void calc_f(const float* __restrict__ v, const float* __restrict__ g,
                       double* __restrict__ f, int O, int C) {
    int o = blockIdx.x;
    const float* row = v + (size_t)o * C;
    double s = 0.0;
    for (int c = threadIdx.x; c < C; c += blockDim.x) {
        double x = (double)row[c];
        s += x * x;
    }
    for (int off = 32; off; off >>= 1) s += __shfl_down(s, off);
    __shared__ double wsum[4];
    int lane = threadIdx.x & 63, wv = threadIdx.x >> 6;
    if (lane == 0) wsum[wv] = s;
    __syncthreads();
    if (threadIdx.x == 0) {
        double tot = 0.0;
        for (int i = 0; i < (int)(blockDim.x >> 6); ++i) tot += wsum[i];
        f[o] = (double)g[o] / sqrt(tot);
    }
}

// wt[c*ldo + o] = v[o*C + c] * f[o]   (double)
__global__ void transpose_scale(const float* __restrict__ v, const double* __restrict__ f,
                                double* __restrict__ wt, int O, int C, int ldo) {
    __shared__ double tile[32][33];
    int c0 = blockIdx.x * 32, o0 = blockIdx.y * 32;
    int tx = threadIdx.x, ty = threadIdx.y;
    for (int k = 0; k < 4; ++k) {
        int o = o0 + ty + k * 8, c = c0 + tx;
        double val = 0.0;
        if (o < O && c < C) val = (double)v[(size_t)o * C + c] * f[o];
        tile[ty + k * 8][tx] = val;
    }
    __syncthreads();
    for (int k = 0; k < 4; ++k) {
        int c = c0 + ty + k * 8, o = o0 + tx;
        if (c < C && o < O) wt[(size_t)c * ldo + o] = tile[tx][ty + k * 8];
    }
}

// ---------------- spike -> bitmask precompute ----------------
// bits[(b*C1 + c)*10 + t32] : bit j = (X[b][c][t32*32+j] != 0)
__global__ void build_bits(const float* __restrict__ X, unsigned* __restrict__ bits) {
    size_t idx = (size_t)blockIdx.x * 256 + threadIdx.x;
    if (idx >= (size_t)B_ * C1_ * 10) return;
    int t32 = (int)(idx % 10);
    size_t bc = idx / 10;
    const float* src = X + bc * T_ + t32 * 32;
    int nq = (t32 == 9) ? 3 : 8;   // 12 or 32 valid t's (T_=300)
    unsigned m = 0;
    for (int q = 0; q < nq; ++q) {
        float4 v = *(const float4*)(src + q * 4);
        if (v.x != 0.f) m |= 1u << (q * 4 + 0);
        if (v.y != 0.f) m |= 1u << (q * 4 + 1);
        if (v.z != 0.f) m |= 1u << (q * 4 + 2);
        if (v.w != 0.f) m |= 1u << (q * 4 + 3);
    }
    bits[idx] = m;
}

// ---------------- GEMM layer 1 (f64, Xbits + SGPR-branch skip + XCD-pinned W) ----------------
// Xbits: [B, C1, 10] u32 ; Wt: [C1, O1] f64 ; Z: [B, T, O1] f64 (ZEROED)
// 1-D grid of 1280 blocks. xg = blockIdx.x & 7 is the round-robin
// block->XCD coordinate: combo = xg & 3 fixes (khalf, o-half), so each XCD's
// L2 holds exactly ONE 2.37 MB W slice (fits 4 MB) -> W staging reads hit L2
// instead of L3.  b = (n>>3)/10*2 + (xg>>2), tb = (n>>3)%10.
// Body identical to R13: SGPR mask branches, f64 atomicAdd K-split combine.
__global__ __launch_bounds__(256) void gemm1(const unsigned* __restrict__ Xbits,
                                             const double* __restrict__ Wt,
                                             double* __restrict__ Z) {
    __shared__ double Ws[16][256];   // [k][o] 32 KB
    int n = blockIdx.x;
    int xg = n & 7;
    int combo = xg & 3;
    int khalf = combo & 1;
    int o0 = (combo >> 1) * 256;
    int i = n >> 3;                      // 0..159
    int tb = i % 10;                     // 32-t window index
    int b = (i / 10) * 2 + (xg >> 2);    // 0..31
    int cbeg = khalf ? KSPLIT_ : 0;
    const int NT = khalf ? 73 : 72;
    int tid = threadIdx.x;
    int lane = tid & 63;
    int w8s = __builtin_amdgcn_readfirstlane((tid >> 6) << 3);  // wave's t-octet offset
    double acc[8][4];
#pragma unroll
    for (int tj = 0; tj < 8; ++tj)
#pragma unroll
        for (int i2 = 0; i2 < 4; ++i2) acc[tj][i2] = 0.0;
    const unsigned* xbp = Xbits + (size_t)b * C1_ * 10 + tb;

    double2 wreg[8];
    unsigned mk[16], mkn[16];

    auto load_w = [&](int c0) {
#pragma unroll
        for (int h = 0; h < 8; ++h) {
            int idx = h * 256 + tid;
            int r = idx >> 7, od = (idx & 127) * 2;
            int c = c0 + r;
            double2 val; val.x = 0.0; val.y = 0.0;
            if (c < C1_) val = *(const double2*)(Wt + (size_t)c * O1_ + o0 + od);
            wreg[h] = val;
        }
    };
    auto load_m = [&](unsigned* dst, int c0) {
#pragma unroll
        for (int k = 0; k < 16; ++k) {
            int c = c0 + k;
            dst[k] = (c < C1_) ? xbp[(size_t)c * 10] : 0u;
        }
    };
    auto store_w = [&]() {
#pragma unroll
        for (int h = 0; h < 8; ++h) {
            int idx = h * 256 + tid;
            int r = idx >> 7, od = (idx & 127) * 2;
            *(double2*)(&Ws[r][od]) = wreg[h];
        }
    };

    load_w(cbeg);
    load_m(mk, cbeg);
    for (int tile = 0; tile < NT; ++tile) {
        store_w();
        __syncthreads();
        if (tile + 1 < NT) {
            int cn = cbeg + (tile + 1) * 16;
            load_w(cn);           // global W -> regs, overlaps inner compute
            load_m(mkn, cn);      // masks for next tile
        }
#pragma unroll
        for (int k = 0; k < 16; ++k) {
            unsigned smk = (unsigned)__builtin_amdgcn_readfirstlane((int)mk[k]);
            unsigned soct = (smk >> w8s) & 0xffu;
            if (soct) {   // wave-uniform scalar branch
                double wf[4];
#pragma unroll
                for (int i2 = 0; i2 < 4; ++i2) wf[i2] = Ws[k][lane + 64 * i2];
#pragma unroll
                for (int tj = 0; tj < 8; ++tj) {
                    if (soct & (1u << tj)) {   // s_cbranch: only useful adds issue
#pragma unroll
                        for (int i2 = 0; i2 < 4; ++i2) acc[tj][i2] += wf[i2];
                    }
                }
            }
        }
#pragma unroll
        for (int k = 0; k < 16; ++k) mk[k] = mkn[k];
        __syncthreads();
    }
#pragma unroll
    for (int tj = 0; tj < 8; ++tj) {
        int t = tb * 32 + w8s + tj;
        if (t < T_) {
            double* dst = Z + ((size_t)b * T_ + t) * O1_ + o0;
#pragma unroll
            for (int i2 = 0; i2 < 4; ++i2)
                atomicAdd(&dst[lane + 64 * i2], acc[tj][i2]);
        }
    }
}

// ---------------- GEMM layer 2 (f64, exact R5 dense version: 0 conflicts) ----------------
// A: s1 [M, 512] f32 (exact 0/1) ; Wt: [512, 512] f64 ; Z: [M, 512] f64
__global__ __launch_bounds__(256) void gemm2(const float* __restrict__ A,
                                             const double* __restrict__ Wt,
                                             double* __restrict__ Z) {
    __shared__ double Ws[16][128];   // [k][o]
    __shared__ double As[64][17];    // [m][k] padded
    int m0 = blockIdx.x * 64;
    int o0 = blockIdx.y * 128;
    int tid = threadIdx.x;
    int to = tid & 15, tm = tid >> 4;
    double acc[8][4];
#pragma unroll
    for (int i = 0; i < 8; ++i)
#pragma unroll
        for (int j = 0; j < 4; ++j) acc[i][j] = 0.0;
    for (int c0 = 0; c0 < 512; c0 += 16) {
        {   // As: thread (m = tid>>2, ch = (tid&3)*4) reads float4, scalar LDS writes
            int m = tid >> 2, ch = (tid & 3) * 4;
            float4 v = *(const float4*)(A + (size_t)(m0 + m) * 512 + c0 + ch);
            As[m][ch + 0] = (double)v.x; As[m][ch + 1] = (double)v.y;
            As[m][ch + 2] = (double)v.z; As[m][ch + 3] = (double)v.w;
        }
#pragma unroll
        for (int h = 0; h < 4; ++h) {   // Ws: linear double2, 2-way = free
            int idx = h * 512 + tid * 2;
            int i = idx >> 7, o = idx & 127;
            *(double2*)(&Ws[i][o]) = *(const double2*)(Wt + (size_t)(c0 + i) * 512 + o0 + o);
        }
        __syncthreads();
#pragma unroll
        for (int k = 0; k < 16; ++k) {
            double wf[8], xf[4];
#pragma unroll
            for (int i = 0; i < 8; ++i) wf[i] = Ws[k][to + 16 * i];
#pragma unroll
            for (int j = 0; j < 4; ++j) xf[j] = As[tm * 4 + j][k];
#pragma unroll
            for (int i = 0; i < 8; ++i)
#pragma unroll
                for (int j = 0; j < 4; ++j) acc[i][j] = fma(wf[i], xf[j], acc[i][j]);
        }
        __syncthreads();
    }
#pragma unroll
    for (int j = 0; j < 4; ++j) {
        double* dst = Z + (size_t)(m0 + tm * 4 + j) * 512 + o0;
#pragma unroll
        for (int i = 0; i < 8; ++i) dst[to + 16 * i] = acc[i][j];
    }
}

// ---------------- GEMM layer 3 (f64 acc) ----------------
__global__ __launch_bounds__(256) void gemm3(const float* __restrict__ A,
                                             const double* __restrict__ Wt,
                                             double* __restrict__ Z) {
    __shared__ double w[512 * 16];
    for (int e = threadIdx.x; e < 4096; e += 256)
        ((double2*)w)[e] = ((const double2*)Wt)[e];
    __syncthreads();
    int m = blockIdx.x * 256 + threadIdx.x;
    if (m >= M_) return;
    double acc[O3_];
#pragma unroll
    for (int o = 0; o < O3_; ++o) acc[o] = 0.0;
    const float4* Ar = (const float4*)(A + (size_t)m * 512);
    for (int cq = 0; cq < 128; ++cq) {
        float4 a = Ar[cq];
        float av[4] = {a.x, a.y, a.z, a.w};
#pragma unroll
        for (int u = 0; u < 4; ++u)
#pragma unroll
            for (int o = 0; o < O3_; ++o) acc[o] += (double)av[u] * w[(cq * 4 + u) * 16 + o];
    }
    double* dst = Z + (size_t)m * 16;
#pragma unroll
    for (int o = 0; o < O3_; ++o) dst[o] = acc[o];
}

// ---------------- LIF scan + delay, layers 1/2 (O=512, f64 state) ----------------
__global__ void scan12(const double* __restrict__ Zin,  // [B, T, 512] f64
                       const int* __restrict__ delay,   // [512]
                       float* __restrict__ Sout,        // [B, T, 512] f32 spikes
                       float* __restrict__ sumOut) {
    int blk = blockIdx.x;
    int o = (blk & 7) * 64 + threadIdx.x;
    int b = blk >> 3;
    const double* z = Zin + (size_t)b * T_ * O1_ + o;
    float* s = Sout + (size_t)b * T_ * O1_ + o;
    int d = delay[o];
    for (int t = 0; t < d; ++t) s[(size_t)t * O1_] = 0.f;
    double cur = 0.0, vol = 0.0;
    float cnt = 0.f;
    // 296 = 37*8; tail of 4 handled after.
    for (int t8 = 0; t8 < 296; t8 += 8) {
        double zb[8];
#pragma unroll
        for (int u = 0; u < 8; ++u) zb[u] = z[(size_t)(t8 + u) * O1_];
#pragma unroll
        for (int u = 0; u < 8; ++u) {
            int t = t8 + u;
            cur = cur * 0.75 + zb[u];
            vol = vol * 0.97 + cur;
            float sp = (vol >= 1.25) ? 1.f : 0.f;
            if (sp > 0.f) vol = 0.0;
            int tw = t + d;
            if (tw < T_) { s[(size_t)tw * O1_] = sp; cnt += sp; }
        }
    }
    {
        double zb[4];
#pragma unroll
        for (int u = 0; u < 4; ++u) zb[u] = z[(size_t)(296 + u) * O1_];
#pragma unroll
        for (int u = 0; u < 4; ++u) {
            int t = 296 + u;
            cur = cur * 0.75 + zb[u];
            vol = vol * 0.97 + cur;
            float sp = (vol >= 1.25) ? 1.f : 0.f;
            if (sp > 0.f) vol = 0.0;
            int tw = t + d;
            if (tw < T_) { s[(size_t)tw * O1_] = sp; cnt += sp; }
        }
    }
    for (int off = 32; off; off >>= 1) cnt += __shfl_down(cnt, off);
    if (threadIdx.x == 0) atomicAdd(sumOut, cnt);
}

// ---------------- LIF scan + delay, layer 3 (O=10, f64 state) ----------------
__global__ void scan3(const double* __restrict__ Z3,  // [M, 16] f64
                      const int* __restrict__ d3,     // [10]
                      float* __restrict__ out,        // d_out: [B, 10, 300] f32
                      float* __restrict__ sumOut) {
    __shared__ double zt[T_ * 16];
    int b = blockIdx.x;
    const double2* src = (const double2*)(Z3 + (size_t)b * T_ * 16);
    for (int e = threadIdx.x; e < T_ * 8; e += 64)
        ((double2*)zt)[e] = src[e];
    __syncthreads();
    int o = threadIdx.x;
    if (o < O3_) {
        int d = d3[o];
        float* dst = out + (size_t)b * O3_ * T_ + (size_t)o * T_;
        for (int t = 0; t < d; ++t) dst[t] = 0.f;
        double cur = 0.0, vol = 0.0;
        float cnt = 0.f;
        for (int t = 0; t < T_; ++t) {
            cur = cur * 0.75 + zt[t * 16 + o];
            vol = vol * 0.97 + cur;
            float sp = (vol >= 1.25) ? 1.f : 0.f;
            if (sp > 0.f) vol = 0.0;
            int tw = t + d;
            if (tw < T_) { dst[tw] = sp; cnt += sp; }
        }
        atomicAdd(sumOut, cnt);
    }
}

__global__ void finalize(const float* __restrict__ sums, float* __restrict__ out) {
    if (threadIdx.x == 0) {
        out[0] = (float)((double)sums[0] / (double)(B_ * O1_ * T_));
        out[1] = (float)((double)sums[1] / (double)(B_ * O2_ * T_));
        out[2] = (float)((double)sums[2] / (double)(B_ * O3_ * T_));
    }
}

extern "C" void kernel_launch(void* const* d_in, const int* in_sizes, int n_in,
                              void* d_out, int out_size, void* d_ws, size_t ws_size,
                              hipStream_t stream) {
    const float* spike = (const float*)d_in[0];
    const float* v1 = (const float*)d_in[1];
    const float* g1 = (const float*)d_in[2];
    const float* v2 = (const float*)d_in[3];
    const float* g2 = (const float*)d_in[4];
    const float* v3 = (const float*)d_in[5];
    const float* g3 = (const float*)d_in[6];
    const int* d1 = (const int*)d_in[7];
    const int* d2 = (const int*)d_in[8];
    const int* d3 = (const int*)d_in[9];
    float* out = (float*)d_out;

    // Workspace: ~75 MB total (R13 layout).
    double* dw = (double*)d_ws;
    size_t off = 0;
    double* f1  = dw + off; off += 512;
    double* f2  = dw + off; off += 512;
    double* f3  = dw + off; off += 16;
    double* Wt1 = dw + off; off += (size_t)C1_ * O1_;
    double* Wt2 = dw + off; off += 512 * 512;
    double* Wt3 = dw + off; off += 512 * 16;
    double* zA  = dw + off; off += (size_t)M_ * 512;
    double* z3b = dw + off; off += (size_t)M_ * 16;
    float* fw = (float*)(dw + off);
    float* sB    = fw;                                   // f32 spikes, M*512
    float* sums  = fw + (size_t)M_ * 512;                // 4 floats
    unsigned* Xbits = (unsigned*)(fw + (size_t)M_ * 512 + 4);  // B*C1*10 u32
    (void)ws_size; (void)out_size; (void)in_sizes; (void)n_in;

    hipMemsetAsync(sums, 0, 4 * sizeof(float), stream);
    hipMemsetAsync(zA, 0, (size_t)M_ * 512 * sizeof(double), stream);  // K-split atomics

    build_bits<<<(B_ * C1_ * 10 + 255) / 256, 256, 0, stream>>>(spike, Xbits);

    calc_f<<<512, 256, 0, stream>>>(v1, g1, f1, O1_, C1_);
    calc_f<<<512, 256, 0, stream>>>(v2, g2, f2, O2_, O1_);
    calc_f<<<O3_, 256, 0, stream>>>(v3, g3, f3, O3_, O2_);

    transpose_scale<<<dim3((C1_ + 31) / 32, 16), dim3(32, 8), 0, stream>>>(v1, f1, Wt1, O1_, C1_, O1_);
    transpose_scale<<<dim3(16, 16), dim3(32, 8), 0, stream>>>(v2, f2, Wt2, O2_, O1_, O2_);
    transpose_scale<<<dim3(16, 1), dim3(32, 8), 0, stream>>>(v3, f3, Wt3, O3_, O2_, 16);

    // gemm1: 1-D grid 1280, XCD-pinned (n&7 -> W-slice combo)
    gemm1<<<1280, 256, 0, stream>>>(Xbits, Wt1, zA);                  // zA += z1
    scan12<<<256, 64, 0, stream>>>(zA, d1, sB, sums + 0);             // sB = s1 (f32)
    gemm2<<<dim3(M_ / 64, 4), 256, 0, stream>>>(sB, Wt2, zA);         // zA = z2 (overwrite)
    scan12<<<256, 64, 0, stream>>>(zA, d2, sB, sums + 1);             // sB = s2
    gemm3<<<(M_ + 255) / 256, 256, 0, stream>>>(sB, Wt3, z3b);        // z3b = z3
    scan3<<<B_, 64, 0, stream>>>(z3b, d3, out, sums + 2);
    finalize<<<1, 64, 0, stream>>>(sums, out + (size_t)B_ * O3_ * T_);
}